// Round 4
// baseline (850.145 us; speedup 1.0000x reference)
//
#include <hip/hip_runtime.h>

#define NN 100000
#define NE 3200000
#define NF 512
#define ND 64
#define NC 10
#define NB 391            // ceil(NN/256)

// workspace layout (4-byte elements)
#define OFF_H      0          // NN*ND  h = x @ (W1*M1); rank[] aliases first NE
#define OFF_RANK   0          //        (consumed by fill before gemm1 writes h)
#define OFF_DIS    6400000    // NN     deg accumulator (hist), then deg^-1/2
#define OFF_W1     6500000    // NF*ND floats = 128KB: B-fragment array (bf16 hi/lo)
#define OFF_CNT    6533408    // NN     int in-degree histogram
#define OFF_RP     6633408    // NN+1   int CSR rowptr
#define OFF_BSUM   6733409    // 512    int block sums for scan
#define OFF_EDGE   6733922    // NE int2 {src, bits(w*dis[src])}  (8B-aligned)
#define OFF_W2F    13133922   // 1024 floats: W2eff bf16 hi/lo frags (64x16, zero-pad)
// total = 13,134,946 * 4B = 52.54 MB

typedef __attribute__((ext_vector_type(8))) short v8s;   // 8 bf16 = 4 VGPRs
typedef __attribute__((ext_vector_type(4))) float v4f;

// round-to-nearest-even fp32 -> bf16 (upper 16 bits)
__device__ __forceinline__ unsigned short bf16_rne(float f) {
  unsigned int u = __float_as_uint(f);
  return (unsigned short)((u + 0x7fffu + ((u >> 16) & 1u)) >> 16);
}

// cnt=0, deg=0, W1eff and W2eff pre-split into bf16 hi/lo MFMA B-fragments.
// Fragment layout (MUST match the consumers):
//   k-step s = k>>5, lane-group g = (k>>3)&3, elem e = k&7, tile t = col>>4,
//   lane = (g<<4)|(col&15).  Halfword offset ((s*T+t)*64+lane)*16 + e (hi), +8 (lo).
// A and B use the SAME k->(g,e) mapping, so the MFMA result is invariant to
// the hardware's internal k-order (any consistent k-permutation cancels).
__global__ __launch_bounds__(256) void prep_kernel(
    const float* __restrict__ W1, const float* __restrict__ M1,
    const float* __restrict__ W2, const float* __restrict__ M2,
    float* __restrict__ ws) {
  const int i = blockIdx.x * 256 + threadIdx.x;   // grid = NB
  if (i < NN) { ((int*)ws)[OFF_CNT + i] = 0; ws[OFF_DIS + i] = 0.0f; }
  if (i < NF * ND) {
    const float v = W1[i] * M1[i];
    const int k = i >> 6, d = i & 63;             // i = k*ND + d
    const int s = k >> 5, g = (k >> 3) & 3, e = k & 7;
    const int t = d >> 4;
    const int lane = (g << 4) | (d & 15);
    unsigned short* bp = (unsigned short*)(ws + OFF_W1);
    const int base = ((s * 4 + t) * 64 + lane) * 16 + e;
    const unsigned short hb = bf16_rne(v);
    bp[base] = hb;
    bp[base + 8] = bf16_rne(v - __uint_as_float((unsigned int)hb << 16));
  }
  if (i < ND * 16) {                              // W2 frags, cols 10..15 zero
    const int k = i >> 4, c = i & 15;
    const float v = (c < NC) ? W2[k * NC + c] * M2[k * NC + c] : 0.0f;
    const int s = k >> 5, g = (k >> 3) & 3, e = k & 7;
    const int lane = (g << 4) | c;
    unsigned short* bp = (unsigned short*)(ws + OFF_W2F);
    const int base = (s * 64 + lane) * 16 + e;
    const unsigned short hb = bf16_rne(v);
    bp[base] = hb;
    bp[base + 8] = bf16_rne(v - __uint_as_float((unsigned int)hb << 16));
  }
}

// the ONLY atomic pass: histogram + intra-bucket rank + weighted in-degree
__global__ __launch_bounds__(256) void hist_kernel(
    const int* __restrict__ dst, const float* __restrict__ ew,
    int* __restrict__ cnt, float* __restrict__ deg, int* __restrict__ rank) {
  const int e = blockIdx.x * 256 + threadIdx.x;   // grid covers exactly NE
  const int d = dst[e];
  rank[e] = atomicAdd(&cnt[d], 1);
  atomicAdd(&deg[d], ew[e]);
}

// per-block sums of cnt -> bsum
__global__ __launch_bounds__(256) void scan_partial(
    const int* __restrict__ cnt, int* __restrict__ bsum) {
  __shared__ int s[256];
  const int i = blockIdx.x * 256 + threadIdx.x;
  int v = (i < NN) ? cnt[i] : 0;
  s[threadIdx.x] = v; __syncthreads();
  for (int off = 128; off > 0; off >>= 1) {
    if (threadIdx.x < off) s[threadIdx.x] += s[threadIdx.x + off];
    __syncthreads();
  }
  if (threadIdx.x == 0) bsum[blockIdx.x] = s[0];
}

// exclusive scan of the NB block sums (single block)
__global__ __launch_bounds__(512) void scan_bsum(int* __restrict__ bsum) {
  __shared__ int s[512];
  const int t = threadIdx.x;
  const int v = (t < NB) ? bsum[t] : 0;
  s[t] = v; __syncthreads();
  for (int off = 1; off < 512; off <<= 1) {
    const int a = (t >= off) ? s[t - off] : 0;
    __syncthreads();
    s[t] += a;
    __syncthreads();
  }
  if (t < NB) bsum[t] = s[t] - v;   // exclusive
}

// per-block exclusive scan + offset -> rowptr; also dis = rsqrt(1+deg)
__global__ __launch_bounds__(256) void scan_final(
    const int* __restrict__ cnt, const int* __restrict__ bsum,
    int* __restrict__ rowptr, float* __restrict__ dis) {
  __shared__ int s[256];
  const int i = blockIdx.x * 256 + threadIdx.x;
  const int v = (i < NN) ? cnt[i] : 0;
  s[threadIdx.x] = v; __syncthreads();
  for (int off = 1; off < 256; off <<= 1) {
    const int a = (threadIdx.x >= off) ? s[threadIdx.x - off] : 0;
    __syncthreads();
    s[threadIdx.x] += a;
    __syncthreads();
  }
  if (i < NN) {
    const int excl = s[threadIdx.x] - v + bsum[blockIdx.x];
    rowptr[i] = excl;
    if (i == NN - 1) rowptr[NN] = excl + v;   // == NE
    dis[i] = rsqrtf(dis[i] + 1.0f);           // +1 = self-loop weight
  }
}

// atomic-free counting-sort fill: edge[rowptr[dst]+rank] = {src, w*dis[src]}
__global__ __launch_bounds__(256) void fill_kernel(
    const int* __restrict__ src, const int* __restrict__ dst,
    const float* __restrict__ ew, const int* __restrict__ rank,
    const int* __restrict__ rowptr, const float* __restrict__ dis,
    int2* __restrict__ edge) {
  const int e = blockIdx.x * 256 + threadIdx.x;   // grid covers exactly NE
  const int sv = src[e];
  const int pos = rowptr[dst[e]] + rank[e];
  edge[pos] = make_int2(sv, __float_as_int(ew[e] * dis[sv]));
}

// h = x @ Weff1 via bf16-split MFMA: x=xh+xl, w=wh+wl (RNE splits),
// acc += xh*wh + xh*wl + xl*wh in fp32 (xl*wl ~2^-18 rel, dropped).
// Wave = 32 nodes x 64 dims: 2 M-frags x 4 N-tiles of 16x16, K-loop 16x32.
// C layout (m89-verified): col = lane&15, row = (lane>>4)*4 + reg.
__global__ __launch_bounds__(256) void gemm1_kernel(
    const float* __restrict__ x, const float* __restrict__ bfrag_f,
    float* __restrict__ h) {
  const int lane = threadIdx.x & 63;
  const int wid  = threadIdx.x >> 6;
  const size_t row0 = ((size_t)blockIdx.x * 4 + wid) * 32;
  if (row0 >= NN) return;
  const int lr = lane & 15;               // A row / B col / C col within tile
  const int lg = lane >> 4;               // k-group
  const float* x0 = x + (row0 + lr) * NF + lg * 8;
  const v8s* bfr = (const v8s*)bfrag_f + (size_t)lane * 2;  // 32B per lane
  v4f acc[2][4];
#pragma unroll
  for (int i = 0; i < 2; ++i)
#pragma unroll
    for (int t = 0; t < 4; ++t) acc[i][t] = (v4f){0.f, 0.f, 0.f, 0.f};

  for (int s = 0; s < 16; ++s) {          // k0 = s*32
    v8s ah[2], al[2];
#pragma unroll
    for (int i = 0; i < 2; ++i) {
      const float* xp = x0 + (size_t)i * (16 * NF) + s * 32;
      const float4 p0 = *(const float4*)xp;
      const float4 p1 = *(const float4*)(xp + 4);
      const float vv[8] = {p0.x, p0.y, p0.z, p0.w, p1.x, p1.y, p1.z, p1.w};
#pragma unroll
      for (int e = 0; e < 8; ++e) {
        const unsigned short hb = bf16_rne(vv[e]);
        ah[i][e] = (short)hb;
        al[i][e] = (short)bf16_rne(vv[e] - __uint_as_float((unsigned int)hb << 16));
      }
    }
#pragma unroll
    for (int t = 0; t < 4; ++t) {
      const v8s bh = bfr[(size_t)(s * 4 + t) * 128];      // hi frag
      const v8s bl = bfr[(size_t)(s * 4 + t) * 128 + 1];  // lo frag
#pragma unroll
      for (int i = 0; i < 2; ++i) {
        acc[i][t] = __builtin_amdgcn_mfma_f32_16x16x32_bf16(ah[i], bh, acc[i][t], 0, 0, 0);
        acc[i][t] = __builtin_amdgcn_mfma_f32_16x16x32_bf16(ah[i], bl, acc[i][t], 0, 0, 0);
        acc[i][t] = __builtin_amdgcn_mfma_f32_16x16x32_bf16(al[i], bh, acc[i][t], 0, 0, 0);
      }
    }
  }
#pragma unroll
  for (int i = 0; i < 2; ++i)
#pragma unroll
    for (int t = 0; t < 4; ++t)
#pragma unroll
      for (int r = 0; r < 4; ++r)
        h[(row0 + i * 16 + lg * 4 + r) * ND + t * 16 + lr] = acc[i][t][r];
}

// One wave per dst node.  Edge list is wave-uniform -> scalar s_load stream;
// p = w*dis[src] was folded in at fill time, so the inner loop is
// 1 scalar edge read + 1 coalesced 256B h-row load + 1 v_fmac (SGPR mult)
// per edge, 8 independent chains.  Epilogue: 4 waves stage relu'd rows in
// LDS; wave 0 runs the 64x10 classifier as one bf16-split MFMA tile.
__global__ __launch_bounds__(256) void gather_kernel(
    const int* __restrict__ rowptr, const int2* __restrict__ edge,
    const float* __restrict__ h, const float* __restrict__ dis,
    const float* __restrict__ b1, const float* __restrict__ w2f,
    const float* __restrict__ b2, float* __restrict__ out) {
  __shared__ float vls[4 * 64];
  const int lane = threadIdx.x & 63;
  const int wid  = threadIdx.x >> 6;
  const int n = blockIdx.x * 4 + wid;              // grid exact: n < NN
  const int beg = __builtin_amdgcn_readfirstlane(rowptr[n]);
  const int end = __builtin_amdgcn_readfirstlane(rowptr[n + 1]);
  float a0 = 0.f, a1 = 0.f, a2 = 0.f, a3 = 0.f,
        a4 = 0.f, a5 = 0.f, a6 = 0.f, a7 = 0.f;
  int e = beg;
  for (; e + 8 <= end; e += 8) {                   // 8 scalar edges, 8 chains
    const int2 q0 = edge[e],     q1 = edge[e + 1];
    const int2 q2 = edge[e + 2], q3 = edge[e + 3];
    const int2 q4 = edge[e + 4], q5 = edge[e + 5];
    const int2 q6 = edge[e + 6], q7 = edge[e + 7];
    a0 = fmaf(h[(size_t)q0.x * ND + lane], __int_as_float(q0.y), a0);
    a1 = fmaf(h[(size_t)q1.x * ND + lane], __int_as_float(q1.y), a1);
    a2 = fmaf(h[(size_t)q2.x * ND + lane], __int_as_float(q2.y), a2);
    a3 = fmaf(h[(size_t)q3.x * ND + lane], __int_as_float(q3.y), a3);
    a4 = fmaf(h[(size_t)q4.x * ND + lane], __int_as_float(q4.y), a4);
    a5 = fmaf(h[(size_t)q5.x * ND + lane], __int_as_float(q5.y), a5);
    a6 = fmaf(h[(size_t)q6.x * ND + lane], __int_as_float(q6.y), a6);
    a7 = fmaf(h[(size_t)q7.x * ND + lane], __int_as_float(q7.y), a7);
  }
  for (; e + 4 <= end; e += 4) {
    const int2 q0 = edge[e],     q1 = edge[e + 1];
    const int2 q2 = edge[e + 2], q3 = edge[e + 3];
    a0 = fmaf(h[(size_t)q0.x * ND + lane], __int_as_float(q0.y), a0);
    a1 = fmaf(h[(size_t)q1.x * ND + lane], __int_as_float(q1.y), a1);
    a2 = fmaf(h[(size_t)q2.x * ND + lane], __int_as_float(q2.y), a2);
    a3 = fmaf(h[(size_t)q3.x * ND + lane], __int_as_float(q3.y), a3);
  }
  for (; e < end; ++e) {
    const int2 q = edge[e];
    a0 = fmaf(h[(size_t)q.x * ND + lane], __int_as_float(q.y), a0);
  }
  const float dn = dis[n];
  const float hn = h[(size_t)n * ND + lane];
  float vv = fmaf((((a0 + a1) + (a2 + a3)) + ((a4 + a5) + (a6 + a7))) + hn * dn,
                  dn, b1[lane]);
  vls[wid * 64 + lane] = fmaxf(vv, 0.0f);
  __syncthreads();
  if (wid == 0) {                                  // 4x64 @ 64x10 via MFMA
    const int lr = lane & 15, lg = lane >> 4;
    const v8s* bfr = (const v8s*)w2f + (size_t)lane * 2;
    v4f acc = (v4f){0.f, 0.f, 0.f, 0.f};
#pragma unroll
    for (int s = 0; s < 2; ++s) {
      v8s ah, al;
#pragma unroll
      for (int k = 0; k < 8; ++k) {
        float xv = vls[(lr & 3) * 64 + s * 32 + lg * 8 + k];
        xv = (lr < 4) ? xv : 0.0f;                 // rows 4..15 zero
        const unsigned short hb = bf16_rne(xv);
        ah[k] = (short)hb;
        al[k] = (short)bf16_rne(xv - __uint_as_float((unsigned int)hb << 16));
      }
      const v8s bh = bfr[s * 128], bl = bfr[s * 128 + 1];
      acc = __builtin_amdgcn_mfma_f32_16x16x32_bf16(ah, bh, acc, 0, 0, 0);
      acc = __builtin_amdgcn_mfma_f32_16x16x32_bf16(ah, bl, acc, 0, 0, 0);
      acc = __builtin_amdgcn_mfma_f32_16x16x32_bf16(al, bh, acc, 0, 0, 0);
    }
    if (lane < NC) {                               // col=lane, rows 0..3 = nodes
      const float bb = b2[lane];
#pragma unroll
      for (int r = 0; r < 4; ++r)
        out[(size_t)(blockIdx.x * 4 + r) * NC + lane] = acc[r] + bb;
    }
  }
}

extern "C" void kernel_launch(void* const* d_in, const int* in_sizes, int n_in,
                              void* d_out, int out_size, void* d_ws, size_t ws_size,
                              hipStream_t stream) {
  const float* x  = (const float*)d_in[0];
  const int*   ei = (const int*)d_in[1];   // (2, NE) row-major int32
  const float* ew = (const float*)d_in[2];
  const float* W1 = (const float*)d_in[3];
  const float* M1 = (const float*)d_in[4];
  const float* b1 = (const float*)d_in[5];
  const float* W2 = (const float*)d_in[6];
  const float* M2 = (const float*)d_in[7];
  const float* b2 = (const float*)d_in[8];
  float* out = (float*)d_out;
  float* ws  = (float*)d_ws;
  int*   wsi = (int*)d_ws;
  const int* src = ei;
  const int* dst = ei + NE;
  int2* edge = (int2*)(wsi + OFF_EDGE);

  prep_kernel<<<NB, 256, 0, stream>>>(W1, M1, W2, M2, ws);
  hist_kernel<<<NE / 256, 256, 0, stream>>>(dst, ew, wsi + OFF_CNT,
                                            ws + OFF_DIS, wsi + OFF_RANK);
  scan_partial<<<NB, 256, 0, stream>>>(wsi + OFF_CNT, wsi + OFF_BSUM);
  scan_bsum<<<1, 512, 0, stream>>>(wsi + OFF_BSUM);
  scan_final<<<NB, 256, 0, stream>>>(wsi + OFF_CNT, wsi + OFF_BSUM,
                                     wsi + OFF_RP, ws + OFF_DIS);
  fill_kernel<<<NE / 256, 256, 0, stream>>>(src, dst, ew, wsi + OFF_RANK,
                                            wsi + OFF_RP, ws + OFF_DIS, edge);
  gemm1_kernel<<<(NN + 127) / 128, 256, 0, stream>>>(x, ws + OFF_W1, ws + OFF_H);
  gather_kernel<<<NN / 4, 256, 0, stream>>>(wsi + OFF_RP, edge, ws + OFF_H,
                                            ws + OFF_DIS, b1, ws + OFF_W2F, b2, out);
}

// Round 5
// 690.530 us; speedup vs baseline: 1.2311x; 1.2311x over previous
//
#include <hip/hip_runtime.h>

#define NN 100000
#define NE 3200000
#define NF 512
#define ND 64
#define NC 10
#define NB 391            // ceil(NN/256)

// workspace layout (4-byte elements)
#define OFF_H      0          // NN*ND  h' = dis*(x @ W1eff); rank[] aliases first NE
#define OFF_RANK   0          //        (consumed by fill before gemm1 writes h)
#define OFF_DIS    6400000    // NN     deg^-1/2 (written by degdis)
#define OFF_W1     6500000    // NF*ND floats = 128KB: B-fragment array (bf16 hi/lo)
#define OFF_CNT    6533408    // NN     int in-degree histogram
#define OFF_RP     6633408    // NN+1   int CSR rowptr
#define OFF_BSUM   6733409    // 512    int block sums for scan
#define OFF_EDGE   6733922    // NE int2 {src, bits(w)}  (8B-aligned)
#define OFF_W2F    13133922   // 1024 floats: W2eff bf16 hi/lo frags (64x16, zero-pad)
// total = 13,134,946 * 4B = 52.54 MB

typedef __attribute__((ext_vector_type(8))) short v8s;   // 8 bf16 = 4 VGPRs
typedef __attribute__((ext_vector_type(4))) float v4f;

// round-to-nearest-even fp32 -> bf16 (upper 16 bits)
__device__ __forceinline__ unsigned short bf16_rne(float f) {
  unsigned int u = __float_as_uint(f);
  return (unsigned short)((u + 0x7fffu + ((u >> 16) & 1u)) >> 16);
}

// cnt=0, W1eff and W2eff pre-split into bf16 hi/lo MFMA B-fragments.
// Fragment layout (MUST match the consumers):
//   k-step s = k>>5, lane-group g = (k>>3)&3, elem e = k&7, tile t = col>>4,
//   lane = (g<<4)|(col&15).  Halfword offset ((s*T+t)*64+lane)*16 + e (hi), +8 (lo).
// A and B use the SAME k->(g,e) mapping, so the MFMA result is invariant to
// the hardware's internal k-order (any consistent k-permutation cancels).
__global__ __launch_bounds__(256) void prep_kernel(
    const float* __restrict__ W1, const float* __restrict__ M1,
    const float* __restrict__ W2, const float* __restrict__ M2,
    float* __restrict__ ws) {
  const int i = blockIdx.x * 256 + threadIdx.x;   // grid = NB
  if (i < NN) ((int*)ws)[OFF_CNT + i] = 0;
  if (i < NF * ND) {
    const float v = W1[i] * M1[i];
    const int k = i >> 6, d = i & 63;             // i = k*ND + d
    const int s = k >> 5, g = (k >> 3) & 3, e = k & 7;
    const int t = d >> 4;
    const int lane = (g << 4) | (d & 15);
    unsigned short* bp = (unsigned short*)(ws + OFF_W1);
    const int base = ((s * 4 + t) * 64 + lane) * 16 + e;
    const unsigned short hb = bf16_rne(v);
    bp[base] = hb;
    bp[base + 8] = bf16_rne(v - __uint_as_float((unsigned int)hb << 16));
  }
  if (i < ND * 16) {                              // W2 frags, cols 10..15 zero
    const int k = i >> 4, c = i & 15;
    const float v = (c < NC) ? W2[k * NC + c] * M2[k * NC + c] : 0.0f;
    const int s = k >> 5, g = (k >> 3) & 3, e = k & 7;
    const int lane = (g << 4) | c;
    unsigned short* bp = (unsigned short*)(ws + OFF_W2F);
    const int base = (s * 64 + lane) * 16 + e;
    const unsigned short hb = bf16_rne(v);
    bp[base] = hb;
    bp[base + 8] = bf16_rne(v - __uint_as_float((unsigned int)hb << 16));
  }
}

// the ONLY atomic pass: histogram + intra-bucket rank.  Device-scope atomics
// resolve at the memory-side coherence point (64B-line RMW each) -- keep this
// to ONE atomic per edge; weighted degree is computed post-sort by degdis.
__global__ __launch_bounds__(256) void hist_kernel(
    const int* __restrict__ dst, int* __restrict__ cnt,
    int* __restrict__ rank) {
  const int e = blockIdx.x * 256 + threadIdx.x;   // grid covers exactly NE
  rank[e] = atomicAdd(&cnt[dst[e]], 1);
}

// per-block sums of cnt -> bsum
__global__ __launch_bounds__(256) void scan_partial(
    const int* __restrict__ cnt, int* __restrict__ bsum) {
  __shared__ int s[256];
  const int i = blockIdx.x * 256 + threadIdx.x;
  int v = (i < NN) ? cnt[i] : 0;
  s[threadIdx.x] = v; __syncthreads();
  for (int off = 128; off > 0; off >>= 1) {
    if (threadIdx.x < off) s[threadIdx.x] += s[threadIdx.x + off];
    __syncthreads();
  }
  if (threadIdx.x == 0) bsum[blockIdx.x] = s[0];
}

// exclusive scan of the NB block sums (single block)
__global__ __launch_bounds__(512) void scan_bsum(int* __restrict__ bsum) {
  __shared__ int s[512];
  const int t = threadIdx.x;
  const int v = (t < NB) ? bsum[t] : 0;
  s[t] = v; __syncthreads();
  for (int off = 1; off < 512; off <<= 1) {
    const int a = (t >= off) ? s[t - off] : 0;
    __syncthreads();
    s[t] += a;
    __syncthreads();
  }
  if (t < NB) bsum[t] = s[t] - v;   // exclusive
}

// per-block exclusive scan + offset -> rowptr
__global__ __launch_bounds__(256) void scan_final(
    const int* __restrict__ cnt, const int* __restrict__ bsum,
    int* __restrict__ rowptr) {
  __shared__ int s[256];
  const int i = blockIdx.x * 256 + threadIdx.x;
  const int v = (i < NN) ? cnt[i] : 0;
  s[threadIdx.x] = v; __syncthreads();
  for (int off = 1; off < 256; off <<= 1) {
    const int a = (threadIdx.x >= off) ? s[threadIdx.x - off] : 0;
    __syncthreads();
    s[threadIdx.x] += a;
    __syncthreads();
  }
  if (i < NN) {
    const int excl = s[threadIdx.x] - v + bsum[blockIdx.x];
    rowptr[i] = excl;
    if (i == NN - 1) rowptr[NN] = excl + v;   // == NE
  }
}

// atomic-free counting-sort fill: edge[rowptr[dst]+rank] = {src, w}
__global__ __launch_bounds__(256) void fill_kernel(
    const int* __restrict__ src, const int* __restrict__ dst,
    const float* __restrict__ ew, const int* __restrict__ rank,
    const int* __restrict__ rowptr, int2* __restrict__ edge) {
  const int e = blockIdx.x * 256 + threadIdx.x;   // grid covers exactly NE
  const int pos = rowptr[dst[e]] + rank[e];
  edge[pos] = make_int2(src[e], __float_as_int(ew[e]));
}

// deg[n] = 1 + row-sum of w; dis = rsqrt(deg). Thread per node.
__global__ __launch_bounds__(256) void degdis_kernel(
    const int* __restrict__ rowptr, const int2* __restrict__ edge,
    float* __restrict__ dis) {
  const int n = blockIdx.x * 256 + threadIdx.x;
  if (n >= NN) return;
  const int beg = rowptr[n], end = rowptr[n + 1];
  float s = 1.0f;                         // self-loop weight
  for (int e = beg; e < end; ++e) s += __int_as_float(edge[e].y);
  dis[n] = rsqrtf(s);
}

// h' = dis * (x @ Weff1) via bf16-split MFMA: x=xh+xl, w=wh+wl (RNE splits),
// acc += xh*wh + xh*wl + xl*wh in fp32 (xl*wl ~2^-18 rel, dropped).
// The dis[row] scale folds the GCN source-normalization into h so the
// gather inner loop needs only the raw edge weight (no dis gather, no
// second atomic pass).  Wave = 32 nodes x 64 dims.
// C layout (m89-verified): col = lane&15, row = (lane>>4)*4 + reg.
__global__ __launch_bounds__(256) void gemm1_kernel(
    const float* __restrict__ x, const float* __restrict__ bfrag_f,
    const float* __restrict__ dis, float* __restrict__ h) {
  const int lane = threadIdx.x & 63;
  const int wid  = threadIdx.x >> 6;
  const size_t row0 = ((size_t)blockIdx.x * 4 + wid) * 32;
  if (row0 >= NN) return;
  const int lr = lane & 15;               // A row / B col / C col within tile
  const int lg = lane >> 4;               // k-group
  const float* x0 = x + (row0 + lr) * NF + lg * 8;
  const v8s* bfr = (const v8s*)bfrag_f + (size_t)lane * 2;  // 32B per lane
  v4f acc[2][4];
#pragma unroll
  for (int i = 0; i < 2; ++i)
#pragma unroll
    for (int t = 0; t < 4; ++t) acc[i][t] = (v4f){0.f, 0.f, 0.f, 0.f};

  for (int s = 0; s < 16; ++s) {          // k0 = s*32
    v8s ah[2], al[2];
#pragma unroll
    for (int i = 0; i < 2; ++i) {
      const float* xp = x0 + (size_t)i * (16 * NF) + s * 32;
      const float4 p0 = *(const float4*)xp;
      const float4 p1 = *(const float4*)(xp + 4);
      const float vv[8] = {p0.x, p0.y, p0.z, p0.w, p1.x, p1.y, p1.z, p1.w};
#pragma unroll
      for (int e = 0; e < 8; ++e) {
        const unsigned short hb = bf16_rne(vv[e]);
        ah[i][e] = (short)hb;
        al[i][e] = (short)bf16_rne(vv[e] - __uint_as_float((unsigned int)hb << 16));
      }
    }
#pragma unroll
    for (int t = 0; t < 4; ++t) {
      const v8s bh = bfr[(size_t)(s * 4 + t) * 128];      // hi frag
      const v8s bl = bfr[(size_t)(s * 4 + t) * 128 + 1];  // lo frag
#pragma unroll
      for (int i = 0; i < 2; ++i) {
        acc[i][t] = __builtin_amdgcn_mfma_f32_16x16x32_bf16(ah[i], bh, acc[i][t], 0, 0, 0);
        acc[i][t] = __builtin_amdgcn_mfma_f32_16x16x32_bf16(ah[i], bl, acc[i][t], 0, 0, 0);
        acc[i][t] = __builtin_amdgcn_mfma_f32_16x16x32_bf16(al[i], bh, acc[i][t], 0, 0, 0);
      }
    }
  }
#pragma unroll
  for (int i = 0; i < 2; ++i)
#pragma unroll
    for (int r = 0; r < 4; ++r) {
      const size_t row = row0 + i * 16 + lg * 4 + r;
      const float dv = dis[row];          // 16-lane broadcast, L1-resident
#pragma unroll
      for (int t = 0; t < 4; ++t)
        h[row * ND + t * 16 + lr] = acc[i][t][r] * dv;
    }
}

// One wave per dst node.  Edge list is wave-uniform -> scalar s_load stream;
// h' already carries dis[src], so the inner loop is 1 scalar edge read +
// 1 coalesced 256B h-row load + 1 v_fmac (SGPR multiplier) per edge,
// 8 independent chains.  Epilogue: out = dis[n]*(sum + h'[n]) + b1, ReLU,
// then 4 waves stage rows in LDS and wave 0 runs the 64x10 classifier as
// one bf16-split MFMA tile.
__global__ __launch_bounds__(256) void gather_kernel(
    const int* __restrict__ rowptr, const int2* __restrict__ edge,
    const float* __restrict__ h, const float* __restrict__ dis,
    const float* __restrict__ b1, const float* __restrict__ w2f,
    const float* __restrict__ b2, float* __restrict__ out) {
  __shared__ float vls[4 * 64];
  const int lane = threadIdx.x & 63;
  const int wid  = threadIdx.x >> 6;
  const int n = blockIdx.x * 4 + wid;              // grid exact: n < NN
  const int beg = __builtin_amdgcn_readfirstlane(rowptr[n]);
  const int end = __builtin_amdgcn_readfirstlane(rowptr[n + 1]);
  float a0 = 0.f, a1 = 0.f, a2 = 0.f, a3 = 0.f,
        a4 = 0.f, a5 = 0.f, a6 = 0.f, a7 = 0.f;
  int e = beg;
  for (; e + 8 <= end; e += 8) {                   // 8 scalar edges, 8 chains
    const int2 q0 = edge[e],     q1 = edge[e + 1];
    const int2 q2 = edge[e + 2], q3 = edge[e + 3];
    const int2 q4 = edge[e + 4], q5 = edge[e + 5];
    const int2 q6 = edge[e + 6], q7 = edge[e + 7];
    a0 = fmaf(h[(size_t)q0.x * ND + lane], __int_as_float(q0.y), a0);
    a1 = fmaf(h[(size_t)q1.x * ND + lane], __int_as_float(q1.y), a1);
    a2 = fmaf(h[(size_t)q2.x * ND + lane], __int_as_float(q2.y), a2);
    a3 = fmaf(h[(size_t)q3.x * ND + lane], __int_as_float(q3.y), a3);
    a4 = fmaf(h[(size_t)q4.x * ND + lane], __int_as_float(q4.y), a4);
    a5 = fmaf(h[(size_t)q5.x * ND + lane], __int_as_float(q5.y), a5);
    a6 = fmaf(h[(size_t)q6.x * ND + lane], __int_as_float(q6.y), a6);
    a7 = fmaf(h[(size_t)q7.x * ND + lane], __int_as_float(q7.y), a7);
  }
  for (; e + 4 <= end; e += 4) {
    const int2 q0 = edge[e],     q1 = edge[e + 1];
    const int2 q2 = edge[e + 2], q3 = edge[e + 3];
    a0 = fmaf(h[(size_t)q0.x * ND + lane], __int_as_float(q0.y), a0);
    a1 = fmaf(h[(size_t)q1.x * ND + lane], __int_as_float(q1.y), a1);
    a2 = fmaf(h[(size_t)q2.x * ND + lane], __int_as_float(q2.y), a2);
    a3 = fmaf(h[(size_t)q3.x * ND + lane], __int_as_float(q3.y), a3);
  }
  for (; e < end; ++e) {
    const int2 q = edge[e];
    a0 = fmaf(h[(size_t)q.x * ND + lane], __int_as_float(q.y), a0);
  }
  const float dn = dis[n];
  const float hn = h[(size_t)n * ND + lane];       // = dis[n]*h_raw[n]
  float vv = fmaf((((a0 + a1) + (a2 + a3)) + ((a4 + a5) + (a6 + a7))) + hn,
                  dn, b1[lane]);
  vls[wid * 64 + lane] = fmaxf(vv, 0.0f);
  __syncthreads();
  if (wid == 0) {                                  // 4x64 @ 64x10 via MFMA
    const int lr = lane & 15, lg = lane >> 4;
    const v8s* bfr = (const v8s*)w2f + (size_t)lane * 2;
    v4f acc = (v4f){0.f, 0.f, 0.f, 0.f};
#pragma unroll
    for (int s = 0; s < 2; ++s) {
      v8s ah, al;
#pragma unroll
      for (int k = 0; k < 8; ++k) {
        float xv = vls[(lr & 3) * 64 + s * 32 + lg * 8 + k];
        xv = (lr < 4) ? xv : 0.0f;                 // rows 4..15 zero
        const unsigned short hb = bf16_rne(xv);
        ah[k] = (short)hb;
        al[k] = (short)bf16_rne(xv - __uint_as_float((unsigned int)hb << 16));
      }
      const v8s bh = bfr[s * 128], bl = bfr[s * 128 + 1];
      acc = __builtin_amdgcn_mfma_f32_16x16x32_bf16(ah, bh, acc, 0, 0, 0);
      acc = __builtin_amdgcn_mfma_f32_16x16x32_bf16(ah, bl, acc, 0, 0, 0);
      acc = __builtin_amdgcn_mfma_f32_16x16x32_bf16(al, bh, acc, 0, 0, 0);
    }
    if (lane < NC) {                               // col=lane, rows 0..3 = nodes
      const float bb = b2[lane];
#pragma unroll
      for (int r = 0; r < 4; ++r)
        out[(size_t)(blockIdx.x * 4 + r) * NC + lane] = acc[r] + bb;
    }
  }
}

extern "C" void kernel_launch(void* const* d_in, const int* in_sizes, int n_in,
                              void* d_out, int out_size, void* d_ws, size_t ws_size,
                              hipStream_t stream) {
  const float* x  = (const float*)d_in[0];
  const int*   ei = (const int*)d_in[1];   // (2, NE) row-major int32
  const float* ew = (const float*)d_in[2];
  const float* W1 = (const float*)d_in[3];
  const float* M1 = (const float*)d_in[4];
  const float* b1 = (const float*)d_in[5];
  const float* W2 = (const float*)d_in[6];
  const float* M2 = (const float*)d_in[7];
  const float* b2 = (const float*)d_in[8];
  float* out = (float*)d_out;
  float* ws  = (float*)d_ws;
  int*   wsi = (int*)d_ws;
  const int* src = ei;
  const int* dst = ei + NE;
  int2* edge = (int2*)(wsi + OFF_EDGE);

  prep_kernel<<<NB, 256, 0, stream>>>(W1, M1, W2, M2, ws);
  hist_kernel<<<NE / 256, 256, 0, stream>>>(dst, wsi + OFF_CNT, wsi + OFF_RANK);
  scan_partial<<<NB, 256, 0, stream>>>(wsi + OFF_CNT, wsi + OFF_BSUM);
  scan_bsum<<<1, 512, 0, stream>>>(wsi + OFF_BSUM);
  scan_final<<<NB, 256, 0, stream>>>(wsi + OFF_CNT, wsi + OFF_BSUM, wsi + OFF_RP);
  fill_kernel<<<NE / 256, 256, 0, stream>>>(src, dst, ew, wsi + OFF_RANK,
                                            wsi + OFF_RP, edge);
  degdis_kernel<<<NB, 256, 0, stream>>>(wsi + OFF_RP, edge, ws + OFF_DIS);
  gemm1_kernel<<<(NN + 127) / 128, 256, 0, stream>>>(x, ws + OFF_W1,
                                                     ws + OFF_DIS, ws + OFF_H);
  gather_kernel<<<NN / 4, 256, 0, stream>>>(wsi + OFF_RP, edge, ws + OFF_H,
                                            ws + OFF_DIS, b1, ws + OFF_W2F, b2, out);
}

// Round 6
// 553.001 us; speedup vs baseline: 1.5373x; 1.2487x over previous
//
#include <hip/hip_runtime.h>

#define NN 100000
#define NE 3200000
#define NF 512
#define ND 64
#define NC 10

#define NBUCK 196         // coarse buckets: dst>>9  (99999>>9 = 195)
#define NPB 500           // partition blocks
#define EPB 6400          // edges per partition block (NE/NPB)

// workspace layout (4-byte elements)
#define OFF_H      0          // NN*ND  h' = dis*(x @ W1eff); buck[] aliases (NE int2)
#define OFF_DIS    6400000    // NN     deg^-1/2 (written by bucket_sort)
#define OFF_W1     6500000    // NF*ND floats = 128KB: B-fragment array (bf16 hi/lo)
#define OFF_GH     6533408    // NBUCK*NPB = 98000 ints: per-(bin,block) histogram
#define OFF_RP     6633408    // NN+1   int CSR rowptr
#define OFF_BSUM   6733409    // 512 ints: T at +0, TS (197) at +256
#define OFF_EDGE   6733922    // NE int2 {src, bits(w)}  (8B-aligned)
#define OFF_W2F    13133922   // 1024 floats: W2eff bf16 hi/lo frags (64x16, zero-pad)
// total = 13,134,946 * 4B = 52.54 MB

typedef __attribute__((ext_vector_type(8))) short v8s;   // 8 bf16 = 4 VGPRs
typedef __attribute__((ext_vector_type(4))) float v4f;

// round-to-nearest-even fp32 -> bf16 (upper 16 bits)
__device__ __forceinline__ unsigned short bf16_rne(float f) {
  unsigned int u = __float_as_uint(f);
  return (unsigned short)((u + 0x7fffu + ((u >> 16) & 1u)) >> 16);
}

// W1eff and W2eff pre-split into bf16 hi/lo MFMA B-fragments.
// Fragment layout (MUST match the consumers):
//   k-step s = k>>5, lane-group g = (k>>3)&3, elem e = k&7, tile t = col>>4,
//   lane = (g<<4)|(col&15).  Halfword offset ((s*T+t)*64+lane)*16 + e (hi), +8 (lo).
// A and B use the SAME k->(g,e) mapping, so the MFMA result is invariant to
// the hardware's internal k-order (any consistent k-permutation cancels).
__global__ __launch_bounds__(256) void prep_kernel(
    const float* __restrict__ W1, const float* __restrict__ M1,
    const float* __restrict__ W2, const float* __restrict__ M2,
    float* __restrict__ ws) {
  const int i = blockIdx.x * 256 + threadIdx.x;   // grid = 128 (covers NF*ND)
  if (i < NF * ND) {
    const float v = W1[i] * M1[i];
    const int k = i >> 6, d = i & 63;             // i = k*ND + d
    const int s = k >> 5, g = (k >> 3) & 3, e = k & 7;
    const int t = d >> 4;
    const int lane = (g << 4) | (d & 15);
    unsigned short* bp = (unsigned short*)(ws + OFF_W1);
    const int base = ((s * 4 + t) * 64 + lane) * 16 + e;
    const unsigned short hb = bf16_rne(v);
    bp[base] = hb;
    bp[base + 8] = bf16_rne(v - __uint_as_float((unsigned int)hb << 16));
  }
  if (i < ND * 16) {                              // W2 frags, cols 10..15 zero
    const int k = i >> 4, c = i & 15;
    const float v = (c < NC) ? W2[k * NC + c] * M2[k * NC + c] : 0.0f;
    const int s = k >> 5, g = (k >> 3) & 3, e = k & 7;
    const int lane = (g << 4) | c;
    unsigned short* bp = (unsigned short*)(ws + OFF_W2F);
    const int base = (s * 64 + lane) * 16 + e;
    const unsigned short hb = bf16_rne(v);
    bp[base] = hb;
    bp[base + 8] = bf16_rne(v - __uint_as_float((unsigned int)hb << 16));
  }
}

// ---- CSR build: two-level counting sort, ZERO global atomics ----
// (device-scope atomics cost ~47ns each at the memory-side coherence point;
//  LDS atomics run at CU-local rates -- the whole build is bandwidth-bound)

// Pass A1: per-block coarse histogram (196 bins) via LDS atomics.
__global__ __launch_bounds__(256) void part_hist(
    const int* __restrict__ dst, int* __restrict__ GH) {
  __shared__ int hist[NBUCK];
  const int tid = threadIdx.x;
  for (int i = tid; i < NBUCK; i += 256) hist[i] = 0;
  __syncthreads();
  const int s0 = blockIdx.x * EPB;
  for (int e = s0 + tid; e < s0 + EPB; e += 256)
    atomicAdd(&hist[dst[e] >> 9], 1);
  __syncthreads();
  for (int i = tid; i < NBUCK; i += 256)
    GH[i * NPB + blockIdx.x] = hist[i];            // bin-major for the scan
}

// Pass A2: per-bin exclusive scan over the NPB block counts (in place),
// bin totals to T.
__global__ __launch_bounds__(512) void part_scan(
    int* __restrict__ GH, int* __restrict__ T) {
  __shared__ int s[512];
  const int t = threadIdx.x;
  const int b = blockIdx.x;                        // bin
  const int v = (t < NPB) ? GH[b * NPB + t] : 0;
  s[t] = v; __syncthreads();
  for (int off = 1; off < 512; off <<= 1) {
    const int a = (t >= off) ? s[t - off] : 0;
    __syncthreads();
    s[t] += a;
    __syncthreads();
  }
  if (t < NPB) GH[b * NPB + t] = s[t] - v;         // exclusive within bin
  if (t == 511) T[b] = s[511];                     // bin total
}

// Pass A3: exclusive scan of the 196 bin totals -> TS (+ sentinel TS[196]=NE).
__global__ __launch_bounds__(256) void part_scan_t(
    const int* __restrict__ T, int* __restrict__ TS) {
  __shared__ int s[256];
  const int t = threadIdx.x;
  const int v = (t < NBUCK) ? T[t] : 0;
  s[t] = v; __syncthreads();
  for (int off = 1; off < 256; off <<= 1) {
    const int a = (t >= off) ? s[t - off] : 0;
    __syncthreads();
    s[t] += a;
    __syncthreads();
  }
  if (t < NBUCK) TS[t] = s[t] - v;
  if (t == NBUCK - 1) TS[NBUCK] = s[t];            // == NE
}

// Pass A4: scatter edges into coarse-bucket runs.  Each block's range within
// each bucket is exclusive (prefix-scanned), rank via LDS cursor.
// Pack: src (17b) | fine-dst (9b) << 17;  w as float bits.
__global__ __launch_bounds__(256) void part_scatter(
    const int* __restrict__ src, const int* __restrict__ dst,
    const float* __restrict__ ew, const int* __restrict__ GH,
    const int* __restrict__ TS, int2* __restrict__ buck) {
  __shared__ int cursor[NBUCK];
  const int tid = threadIdx.x;
  for (int i = tid; i < NBUCK; i += 256)
    cursor[i] = GH[i * NPB + blockIdx.x] + TS[i];
  __syncthreads();
  const int s0 = blockIdx.x * EPB;
  for (int e = s0 + tid; e < s0 + EPB; e += 256) {
    const int d = dst[e];
    const int pos = atomicAdd(&cursor[d >> 9], 1);
    buck[pos] = make_int2(src[e] | ((d & 511) << 17), __float_as_int(ew[e]));
  }
}

// Pass B: one block per coarse bucket (512 fine bins = 512 nodes).
// Read 1: fine histogram + weighted-degree (both LDS atomics, same read).
// In-block scan -> rowptr + dis.  Read 2: scatter to final CSR edge array.
// Replaces scan_partial/scan_bsum/scan_final + fill + degdis.
__global__ __launch_bounds__(512) void bucket_sort(
    const int* __restrict__ TS, const int2* __restrict__ buck,
    int2* __restrict__ edge, int* __restrict__ rowptr,
    float* __restrict__ dis) {
  __shared__ int hist[512];
  __shared__ float deg[512];
  __shared__ int scn[512];
  const int t = threadIdx.x;
  const int b = blockIdx.x;
  const int beg = TS[b], endd = TS[b + 1];
  hist[t] = 0; deg[t] = 0.0f;
  __syncthreads();
  for (int e = beg + t; e < endd; e += 512) {
    const int2 q = buck[e];
    const int fine = (q.x >> 17) & 511;
    atomicAdd(&hist[fine], 1);
    atomicAdd(&deg[fine], __int_as_float(q.y));
  }
  __syncthreads();
  const int sv = hist[t];
  scn[t] = sv; __syncthreads();
  for (int off = 1; off < 512; off <<= 1) {
    const int a = (t >= off) ? scn[t - off] : 0;
    __syncthreads();
    scn[t] += a;
    __syncthreads();
  }
  const int ex = scn[t] - sv;                      // exclusive
  const int node = b * 512 + t;
  if (node < NN) {
    rowptr[node] = beg + ex;
    dis[node] = rsqrtf(deg[t] + 1.0f);             // +1 = self-loop weight
  }
  if (b == NBUCK - 1 && t == 0) rowptr[NN] = endd; // == NE
  hist[t] = beg + ex;                              // reuse hist as cursor
  __syncthreads();
  for (int e = beg + t; e < endd; e += 512) {
    const int2 q = buck[e];
    const int fine = (q.x >> 17) & 511;
    const int pos = atomicAdd(&hist[fine], 1);
    edge[pos] = make_int2(q.x & 0x1FFFF, q.y);
  }
}

// h' = dis * (x @ Weff1) via bf16-split MFMA: x=xh+xl, w=wh+wl (RNE splits),
// acc += xh*wh + xh*wl + xl*wh in fp32 (xl*wl ~2^-18 rel, dropped).
// The dis[row] scale folds the GCN source-normalization into h so the
// gather inner loop needs only the raw edge weight.  Wave = 32 nodes x 64 dims.
// C layout (m89-verified): col = lane&15, row = (lane>>4)*4 + reg.
__global__ __launch_bounds__(256) void gemm1_kernel(
    const float* __restrict__ x, const float* __restrict__ bfrag_f,
    const float* __restrict__ dis, float* __restrict__ h) {
  const int lane = threadIdx.x & 63;
  const int wid  = threadIdx.x >> 6;
  const size_t row0 = ((size_t)blockIdx.x * 4 + wid) * 32;
  if (row0 >= NN) return;
  const int lr = lane & 15;               // A row / B col / C col within tile
  const int lg = lane >> 4;               // k-group
  const float* x0 = x + (row0 + lr) * NF + lg * 8;
  const v8s* bfr = (const v8s*)bfrag_f + (size_t)lane * 2;  // 32B per lane
  v4f acc[2][4];
#pragma unroll
  for (int i = 0; i < 2; ++i)
#pragma unroll
    for (int t = 0; t < 4; ++t) acc[i][t] = (v4f){0.f, 0.f, 0.f, 0.f};

  for (int s = 0; s < 16; ++s) {          // k0 = s*32
    v8s ah[2], al[2];
#pragma unroll
    for (int i = 0; i < 2; ++i) {
      const float* xp = x0 + (size_t)i * (16 * NF) + s * 32;
      const float4 p0 = *(const float4*)xp;
      const float4 p1 = *(const float4*)(xp + 4);
      const float vv[8] = {p0.x, p0.y, p0.z, p0.w, p1.x, p1.y, p1.z, p1.w};
#pragma unroll
      for (int e = 0; e < 8; ++e) {
        const unsigned short hb = bf16_rne(vv[e]);
        ah[i][e] = (short)hb;
        al[i][e] = (short)bf16_rne(vv[e] - __uint_as_float((unsigned int)hb << 16));
      }
    }
#pragma unroll
    for (int t = 0; t < 4; ++t) {
      const v8s bh = bfr[(size_t)(s * 4 + t) * 128];      // hi frag
      const v8s bl = bfr[(size_t)(s * 4 + t) * 128 + 1];  // lo frag
#pragma unroll
      for (int i = 0; i < 2; ++i) {
        acc[i][t] = __builtin_amdgcn_mfma_f32_16x16x32_bf16(ah[i], bh, acc[i][t], 0, 0, 0);
        acc[i][t] = __builtin_amdgcn_mfma_f32_16x16x32_bf16(ah[i], bl, acc[i][t], 0, 0, 0);
        acc[i][t] = __builtin_amdgcn_mfma_f32_16x16x32_bf16(al[i], bh, acc[i][t], 0, 0, 0);
      }
    }
  }
#pragma unroll
  for (int i = 0; i < 2; ++i)
#pragma unroll
    for (int r = 0; r < 4; ++r) {
      const size_t row = row0 + i * 16 + lg * 4 + r;
      const float dv = dis[row];          // 16-lane broadcast, L1-resident
#pragma unroll
      for (int t = 0; t < 4; ++t)
        h[row * ND + t * 16 + lr] = acc[i][t][r] * dv;
    }
}

// One wave per dst node.  Edge list is wave-uniform -> scalar s_load stream;
// h' already carries dis[src], so the inner loop is 1 scalar edge read +
// 1 coalesced 256B h-row load + 1 v_fmac (SGPR multiplier) per edge,
// 8 independent chains.  Epilogue: out = dis[n]*(sum + h'[n]) + b1, ReLU,
// then 4 waves stage rows in LDS and wave 0 runs the 64x10 classifier as
// one bf16-split MFMA tile.
__global__ __launch_bounds__(256) void gather_kernel(
    const int* __restrict__ rowptr, const int2* __restrict__ edge,
    const float* __restrict__ h, const float* __restrict__ dis,
    const float* __restrict__ b1, const float* __restrict__ w2f,
    const float* __restrict__ b2, float* __restrict__ out) {
  __shared__ float vls[4 * 64];
  const int lane = threadIdx.x & 63;
  const int wid  = threadIdx.x >> 6;
  const int n = blockIdx.x * 4 + wid;              // grid exact: n < NN
  const int beg = __builtin_amdgcn_readfirstlane(rowptr[n]);
  const int end = __builtin_amdgcn_readfirstlane(rowptr[n + 1]);
  float a0 = 0.f, a1 = 0.f, a2 = 0.f, a3 = 0.f,
        a4 = 0.f, a5 = 0.f, a6 = 0.f, a7 = 0.f;
  int e = beg;
  for (; e + 8 <= end; e += 8) {                   // 8 scalar edges, 8 chains
    const int2 q0 = edge[e],     q1 = edge[e + 1];
    const int2 q2 = edge[e + 2], q3 = edge[e + 3];
    const int2 q4 = edge[e + 4], q5 = edge[e + 5];
    const int2 q6 = edge[e + 6], q7 = edge[e + 7];
    a0 = fmaf(h[(size_t)q0.x * ND + lane], __int_as_float(q0.y), a0);
    a1 = fmaf(h[(size_t)q1.x * ND + lane], __int_as_float(q1.y), a1);
    a2 = fmaf(h[(size_t)q2.x * ND + lane], __int_as_float(q2.y), a2);
    a3 = fmaf(h[(size_t)q3.x * ND + lane], __int_as_float(q3.y), a3);
    a4 = fmaf(h[(size_t)q4.x * ND + lane], __int_as_float(q4.y), a4);
    a5 = fmaf(h[(size_t)q5.x * ND + lane], __int_as_float(q5.y), a5);
    a6 = fmaf(h[(size_t)q6.x * ND + lane], __int_as_float(q6.y), a6);
    a7 = fmaf(h[(size_t)q7.x * ND + lane], __int_as_float(q7.y), a7);
  }
  for (; e + 4 <= end; e += 4) {
    const int2 q0 = edge[e],     q1 = edge[e + 1];
    const int2 q2 = edge[e + 2], q3 = edge[e + 3];
    a0 = fmaf(h[(size_t)q0.x * ND + lane], __int_as_float(q0.y), a0);
    a1 = fmaf(h[(size_t)q1.x * ND + lane], __int_as_float(q1.y), a1);
    a2 = fmaf(h[(size_t)q2.x * ND + lane], __int_as_float(q2.y), a2);
    a3 = fmaf(h[(size_t)q3.x * ND + lane], __int_as_float(q3.y), a3);
  }
  for (; e < end; ++e) {
    const int2 q = edge[e];
    a0 = fmaf(h[(size_t)q.x * ND + lane], __int_as_float(q.y), a0);
  }
  const float dn = dis[n];
  const float hn = h[(size_t)n * ND + lane];       // = dis[n]*h_raw[n]
  float vv = fmaf((((a0 + a1) + (a2 + a3)) + ((a4 + a5) + (a6 + a7))) + hn,
                  dn, b1[lane]);
  vls[wid * 64 + lane] = fmaxf(vv, 0.0f);
  __syncthreads();
  if (wid == 0) {                                  // 4x64 @ 64x10 via MFMA
    const int lr = lane & 15, lg = lane >> 4;
    const v8s* bfr = (const v8s*)w2f + (size_t)lane * 2;
    v4f acc = (v4f){0.f, 0.f, 0.f, 0.f};
#pragma unroll
    for (int s = 0; s < 2; ++s) {
      v8s ah, al;
#pragma unroll
      for (int k = 0; k < 8; ++k) {
        float xv = vls[(lr & 3) * 64 + s * 32 + lg * 8 + k];
        xv = (lr < 4) ? xv : 0.0f;                 // rows 4..15 zero
        const unsigned short hb = bf16_rne(xv);
        ah[k] = (short)hb;
        al[k] = (short)bf16_rne(xv - __uint_as_float((unsigned int)hb << 16));
      }
      const v8s bh = bfr[s * 128], bl = bfr[s * 128 + 1];
      acc = __builtin_amdgcn_mfma_f32_16x16x32_bf16(ah, bh, acc, 0, 0, 0);
      acc = __builtin_amdgcn_mfma_f32_16x16x32_bf16(ah, bl, acc, 0, 0, 0);
      acc = __builtin_amdgcn_mfma_f32_16x16x32_bf16(al, bh, acc, 0, 0, 0);
    }
    if (lane < NC) {                               // col=lane, rows 0..3 = nodes
      const float bb = b2[lane];
#pragma unroll
      for (int r = 0; r < 4; ++r)
        out[(size_t)(blockIdx.x * 4 + r) * NC + lane] = acc[r] + bb;
    }
  }
}

extern "C" void kernel_launch(void* const* d_in, const int* in_sizes, int n_in,
                              void* d_out, int out_size, void* d_ws, size_t ws_size,
                              hipStream_t stream) {
  const float* x  = (const float*)d_in[0];
  const int*   ei = (const int*)d_in[1];   // (2, NE) row-major int32
  const float* ew = (const float*)d_in[2];
  const float* W1 = (const float*)d_in[3];
  const float* M1 = (const float*)d_in[4];
  const float* b1 = (const float*)d_in[5];
  const float* W2 = (const float*)d_in[6];
  const float* M2 = (const float*)d_in[7];
  const float* b2 = (const float*)d_in[8];
  float* out = (float*)d_out;
  float* ws  = (float*)d_ws;
  int*   wsi = (int*)d_ws;
  const int* src = ei;
  const int* dst = ei + NE;
  int2* buck = (int2*)(ws + OFF_H);        // aliases h, consumed pre-gemm1
  int2* edge = (int2*)(wsi + OFF_EDGE);
  int*  GH   = wsi + OFF_GH;
  int*  T    = wsi + OFF_BSUM;
  int*  TS   = wsi + OFF_BSUM + 256;

  prep_kernel<<<128, 256, 0, stream>>>(W1, M1, W2, M2, ws);
  part_hist<<<NPB, 256, 0, stream>>>(dst, GH);
  part_scan<<<NBUCK, 512, 0, stream>>>(GH, T);
  part_scan_t<<<1, 256, 0, stream>>>(T, TS);
  part_scatter<<<NPB, 256, 0, stream>>>(src, dst, ew, GH, TS, buck);
  bucket_sort<<<NBUCK, 512, 0, stream>>>(TS, buck, edge, wsi + OFF_RP,
                                         ws + OFF_DIS);
  gemm1_kernel<<<(NN + 127) / 128, 256, 0, stream>>>(x, ws + OFF_W1,
                                                     ws + OFF_DIS, ws + OFF_H);
  gather_kernel<<<NN / 4, 256, 0, stream>>>(wsi + OFF_RP, edge, ws + OFF_H,
                                            ws + OFF_DIS, b1, ws + OFF_W2F, b2, out);
}